// Round 1
// baseline (159.464 us; speedup 1.0000x reference)
//
#include <hip/hip_runtime.h>

#define CN 144
#define VN 576
#define BN 1024
#define NITER 3
#define ECAP 3072   // expected n_edges = 2304 (+ rare row-fix additions)

// d_ws layout (ints): [0] n_edges ; [1 .. 1+CN] row_ptr (CN+1) ; [2+CN ...] packed edges (c<<16)|v
__global__ __launch_bounds__(256) void ldpc_build(const float* __restrict__ H,
                                                  int* __restrict__ adj) {
    __shared__ int rlen[CN];
    __shared__ int rptr[CN + 1];
    const int t = threadIdx.x;
    for (int c = t; c < CN; c += blockDim.x) {
        const float* row = H + c * VN;
        int cnt = 0;
        for (int v = 0; v < VN; ++v) cnt += (row[v] > 0.5f) ? 1 : 0;
        rlen[c] = cnt;
    }
    __syncthreads();
    if (t == 0) {
        int acc = 0;
        for (int c = 0; c < CN; ++c) { rptr[c] = acc; acc += rlen[c]; }
        rptr[CN] = acc;
        adj[0] = acc;
    }
    __syncthreads();
    for (int i = t; i <= CN; i += blockDim.x) adj[1 + i] = rptr[i];
    for (int c = t; c < CN; c += blockDim.x) {
        const float* row = H + c * VN;
        int o = rptr[c];
        for (int v = 0; v < VN; ++v) {          // increasing v => argmin tie-break matches jnp
            if (row[v] > 0.5f) { adj[2 + CN + o] = (c << 16) | v; ++o; }
        }
    }
}

__global__ __launch_bounds__(256) void ldpc_decode(const float* __restrict__ r,
                                                   const float* __restrict__ alpha,
                                                   const int* __restrict__ adj,
                                                   float* __restrict__ out) {
    __shared__ float r_s[VN];
    __shared__ float colsum[VN];
    __shared__ float M_s[ECAP];
    __shared__ int   cv_s[ECAP];
    __shared__ int   rptr_s[CN + 1];
    __shared__ float cmin1[CN], cmin2[CN], csgn[CN];
    __shared__ int   cargm[CN];

    const int b = blockIdx.x;
    const int t = threadIdx.x;
    const int nE = adj[0];

    for (int i = t; i <= CN; i += 256) rptr_s[i] = adj[1 + i];
    for (int v = t; v < VN; v += 256) r_s[v] = r[b * VN + v];
    __syncthreads();
    for (int e = t; e < nE; e += 256) {
        const int cv = adj[2 + CN + e];
        cv_s[e] = cv;
        M_s[e] = r_s[cv & 0xFFFF];   // M init = r on edges
    }
    __syncthreads();

    for (int it = 0; it < NITER; ++it) {
        const float a = alpha[it];

        // zero colsum + per-check aggregates (min1, min2, first-argmin, sign product)
        for (int v = t; v < VN; v += 256) colsum[v] = 0.0f;
        for (int c = t; c < CN; c += 256) {
            const int s = rptr_s[c], epast = rptr_s[c + 1];
            float m1 = INFINITY, m2 = INFINITY, sg = 1.0f;
            int am = s;
            for (int e = s; e < epast; ++e) {
                const float m  = M_s[e];
                const float ab = fabsf(m);
                sg *= (m > 0.0f) ? 1.0f : ((m < 0.0f) ? -1.0f : 0.0f);
                if (ab < m1)      { m2 = m1; m1 = ab; am = e; }   // strict <: first occurrence
                else if (ab < m2) { m2 = ab; }                    // captures tied duplicate
            }
            cmin1[c] = m1; cmin2[c] = m2; csgn[c] = sg; cargm[c] = am;
        }
        __syncthreads();

        // per-edge E: E = a * row_sign * sign(m) * excl_min ; store E in place of M
        for (int e = t; e < nE; e += 256) {
            const int cv = cv_s[e];
            const int c = cv >> 16, v = cv & 0xFFFF;
            const float m    = M_s[e];
            const float sg   = (m > 0.0f) ? 1.0f : ((m < 0.0f) ? -1.0f : 0.0f);
            const float excl = (e == cargm[c]) ? cmin2[c] : cmin1[c];
            const float E    = a * csgn[c] * sg * excl;
            M_s[e] = E;
            atomicAdd(&colsum[v], E);
        }
        __syncthreads();

        // variable update: M = colsum - E + r (skip on last iter; output needs only colsum)
        if (it < NITER - 1) {
            for (int e = t; e < nE; e += 256) {
                const int v = cv_s[e] & 0xFFFF;
                M_s[e] = colsum[v] - M_s[e] + r_s[v];
            }
            __syncthreads();
        }
    }

    for (int v = t; v < VN; v += 256) out[b * VN + v] = r_s[v] + colsum[v];
}

extern "C" void kernel_launch(void* const* d_in, const int* in_sizes, int n_in,
                              void* d_out, int out_size, void* d_ws, size_t ws_size,
                              hipStream_t stream) {
    const float* r     = (const float*)d_in[0];
    const float* alpha = (const float*)d_in[1];
    const float* H     = (const float*)d_in[2];
    float* out = (float*)d_out;
    int* adj   = (int*)d_ws;

    ldpc_build<<<1, 256, 0, stream>>>(H, adj);
    ldpc_decode<<<BN, 256, 0, stream>>>(r, alpha, adj, out);
}

// Round 2
// 80.668 us; speedup vs baseline: 1.9768x; 1.9768x over previous
//
#include <hip/hip_runtime.h>

#define CN 144
#define VN 576
#define BN 1024
#define NITER 3
#define ECAP 3072     // nE expected 2304
#define CCAP 8        // column weight 4 (+ rare row-fix additions)

// ws layout (ints):
#define WS_RLEN 0                 // [0,144)
#define WS_RPTR 144               // [144,289)  rptr[145]; rptr[144] = nE
#define WS_LOC  320               // [320, 320+144*576)  per-(c,v) local offset within row, -1 if no edge
#define WS_CSC  (320 + CN*VN)     // [.., +576*8)  packed (edge_idx<<8)|c, -1 sentinel
#define WS_CCNT (WS_CSC + VN*CCAP)// [.., +576)

// ---- build: per-row ballot compaction -> loc table + row lengths ----
__global__ __launch_bounds__(64) void build_stage(const float* __restrict__ H,
                                                  int* __restrict__ ws) {
    const int c = blockIdx.x;          // 144 blocks
    const int lane = threadIdx.x;      // 64
    int base = 0;
    int* loc = ws + WS_LOC + c * VN;
    const float* row = H + c * VN;
    for (int ch = 0; ch < VN / 64; ++ch) {
        const int v = ch * 64 + lane;
        const bool set = row[v] > 0.5f;
        const unsigned long long mask = __ballot(set);
        const int off = base + __popcll(mask & ((1ULL << lane) - 1ULL));
        loc[v] = set ? off : -1;
        base += (int)__popcll(mask);
    }
    if (lane == 0) ws[WS_RLEN + c] = base;
}

// ---- build: exclusive prefix over 144 row lengths ----
__global__ void build_scan(int* __restrict__ ws) {
    if (threadIdx.x == 0) {
        int acc = 0;
        for (int c = 0; c < CN; ++c) { ws[WS_RPTR + c] = acc; acc += ws[WS_RLEN + c]; }
        ws[WS_RPTR + CN] = acc;
    }
}

// ---- build: CSC (column -> edges), ascending c => deterministic sum order ----
__global__ __launch_bounds__(64) void build_csc(int* __restrict__ ws) {
    const int v = blockIdx.x * 64 + threadIdx.x;   // 9 blocks * 64 = 576
    if (v >= VN) return;
    int cnt = 0;
    for (int c = 0; c < CN; ++c) {
        const int l = ws[WS_LOC + c * VN + v];
        if (l >= 0 && cnt < CCAP) {
            ws[WS_CSC + v * CCAP + cnt] = ((ws[WS_RPTR + c] + l) << 8) | c;
            ++cnt;
        }
    }
    for (int j = cnt; j < CCAP; ++j) ws[WS_CSC + v * CCAP + j] = -1;
    ws[WS_CCNT + v] = cnt;
}

// ---- decode: one block per batch item; no atomics, 2 barriers/iter ----
__global__ __launch_bounds__(256) void ldpc_decode(const float* __restrict__ r,
                                                   const float* __restrict__ alpha,
                                                   const int* __restrict__ ws,
                                                   float* __restrict__ out) {
    __shared__ float r_s[VN];
    __shared__ float M_s[ECAP];
    __shared__ int   rptr_s[CN + 1];
    __shared__ float p1_s[CN], p2_s[CN];   // a * rowsign * {min1,min2}
    __shared__ int   am_s[CN];             // first-argmin edge index
    __shared__ int   csc_s[VN * CCAP];
    __shared__ int   ccnt_s[VN];

    const int b = blockIdx.x;
    const int t = threadIdx.x;

    for (int i = t; i < CN + 1; i += 256) rptr_s[i] = ws[WS_RPTR + i];
    for (int i = t; i < VN; i += 256) {
        r_s[i] = r[b * VN + i];
        ccnt_s[i] = ws[WS_CCNT + i];
    }
    for (int i = t; i < VN * CCAP; i += 256) csc_s[i] = ws[WS_CSC + i];
    __syncthreads();

    // M init = r on edges (via CSC)
    for (int i = t; i < VN * CCAP; i += 256) {
        const int entry = csc_s[i];
        if (entry >= 0) M_s[entry >> 8] = r_s[i >> 3];   // CCAP == 8
    }
    __syncthreads();

    for (int it = 0; it < NITER; ++it) {
        const float a = alpha[it];

        // Pass A: per-check {min1, min2, first-argmin, sign-product}
        for (int c = t; c < CN; c += 256) {
            const int s = rptr_s[c], epst = rptr_s[c + 1];
            float m1 = INFINITY, m2 = INFINITY, sg = 1.0f;
            int am = s;
            for (int e = s; e < epst; ++e) {
                const float m  = M_s[e];
                const float ab = fabsf(m);
                sg *= (m > 0.0f) ? 1.0f : ((m < 0.0f) ? -1.0f : 0.0f);
                if (ab < m1)      { m2 = m1; m1 = ab; am = e; }  // strict <: first occurrence
                else if (ab < m2) { m2 = ab; }
            }
            const float base = a * sg;
            p1_s[c] = base * m1;
            p2_s[c] = base * m2;
            am_s[c] = am;
        }
        __syncthreads();

        // Pass B: per-variable gather of its <=8 edges; fused col-sum + M update
        for (int v = t; v < VN; v += 256) {
            const int cnt = ccnt_s[v];
            float col = 0.0f;
            float Ej[CCAP];
            int   ej[CCAP];
            #pragma unroll
            for (int j = 0; j < CCAP; ++j) {
                float E = 0.0f; int e = -1;
                if (j < cnt) {
                    const int entry = csc_s[v * CCAP + j];
                    e = entry >> 8;
                    const int c = entry & 255;
                    const float m  = M_s[e];
                    const float sg = (m > 0.0f) ? 1.0f : ((m < 0.0f) ? -1.0f : 0.0f);
                    E = sg * ((e == am_s[c]) ? p2_s[c] : p1_s[c]);
                }
                Ej[j] = E; ej[j] = e;
                col += E;
            }
            if (it == NITER - 1) {
                out[b * VN + v] = r_s[v] + col;
            } else {
                const float mbase = col + r_s[v];
                #pragma unroll
                for (int j = 0; j < CCAP; ++j)
                    if (j < cnt) M_s[ej[j]] = mbase - Ej[j];
            }
        }
        __syncthreads();
    }
}

extern "C" void kernel_launch(void* const* d_in, const int* in_sizes, int n_in,
                              void* d_out, int out_size, void* d_ws, size_t ws_size,
                              hipStream_t stream) {
    const float* r     = (const float*)d_in[0];
    const float* alpha = (const float*)d_in[1];
    const float* H     = (const float*)d_in[2];
    float* out = (float*)d_out;
    int* ws    = (int*)d_ws;

    build_stage<<<CN, 64, 0, stream>>>(H, ws);
    build_scan<<<1, 64, 0, stream>>>(ws);
    build_csc<<<(VN + 63) / 64, 64, 0, stream>>>(ws);
    ldpc_decode<<<BN, 256, 0, stream>>>(r, alpha, ws, out);
}

// Round 3
// 36.333 us; speedup vs baseline: 4.3890x; 2.2202x over previous
//
#include <hip/hip_runtime.h>

#define CN 144
#define VN 576
#define BN 1024
#define NITER 3
#define ECAP 3072     // nE expected 2304
#define CCAP 8        // column weight 4 (+ rare row-fix additions)

// ws layout (ints):
#define WS_RLEN 0                 // [0,144)
#define WS_RPTR 144               // [144,289)  rptr[145]; rptr[144] = nE
#define WS_LOC  320               // [320, 320+144*576)  per-(c,v) local offset within row, -1 if no edge
#define WS_CSC  (320 + CN*VN)     // [.., +576*8)  packed (edge_idx<<8)|c, -1 sentinel
#define WS_CCNT (WS_CSC + VN*CCAP)// [.., +576)

// ---- build: per-row ballot compaction -> loc table + row lengths ----
__global__ __launch_bounds__(64) void build_stage(const float* __restrict__ H,
                                                  int* __restrict__ ws) {
    const int c = blockIdx.x;          // 144 blocks
    const int lane = threadIdx.x;      // 64
    int base = 0;
    int* loc = ws + WS_LOC + c * VN;
    const float* row = H + c * VN;
    for (int ch = 0; ch < VN / 64; ++ch) {
        const int v = ch * 64 + lane;
        const bool set = row[v] > 0.5f;
        const unsigned long long mask = __ballot(set);
        const int off = base + __popcll(mask & ((1ULL << lane) - 1ULL));
        loc[v] = set ? off : -1;
        base += (int)__popcll(mask);
    }
    if (lane == 0) ws[WS_RLEN + c] = base;
}

// ---- build: one wave per column; in-register rptr scan + ballot compaction ----
__global__ __launch_bounds__(64) void build_csc(int* __restrict__ ws) {
    const int v = blockIdx.x;          // 576 blocks
    const int lane = threadIdx.x;      // 64
    __shared__ int rptr_s[CN];

    // wave-wide exclusive scan of rlen[0..143] (3 chunks of 64)
    const int x0 = ws[WS_RLEN + lane];
    const int x1 = ws[WS_RLEN + 64 + lane];
    const int x2 = (128 + lane < CN) ? ws[WS_RLEN + 128 + lane] : 0;
    int i0 = x0, i1 = x1, i2 = x2;
    for (int d = 1; d < 64; d <<= 1) {
        const int t0 = __shfl_up(i0, d);
        const int t1 = __shfl_up(i1, d);
        const int t2 = __shfl_up(i2, d);
        if (lane >= d) { i0 += t0; i1 += t1; i2 += t2; }
    }
    const int s0 = __shfl(i0, 63);
    const int s1 = __shfl(i1, 63);
    const int s2 = __shfl(i2, 63);
    const int e0 = i0 - x0;
    const int e1 = s0 + i1 - x1;
    const int e2 = s0 + s1 + i2 - x2;
    rptr_s[lane] = e0;
    rptr_s[64 + lane] = e1;
    if (128 + lane < CN) rptr_s[128 + lane] = e2;
    if (v == 0) {   // publish rptr for decode
        ws[WS_RPTR + lane] = e0;
        ws[WS_RPTR + 64 + lane] = e1;
        if (128 + lane < CN) ws[WS_RPTR + 128 + lane] = e2;
        if (lane == 0) ws[WS_RPTR + CN] = s0 + s1 + s2;
    }
    __syncthreads();

    // ballot-compact column v in ascending-c order
    int cnt = 0;
    for (int ch = 0; ch < 3; ++ch) {
        const int c = ch * 64 + lane;
        const int l = (c < CN) ? ws[WS_LOC + c * VN + v] : -1;
        const bool set = (l >= 0);
        const unsigned long long mask = __ballot(set);
        const int off = cnt + (int)__popcll(mask & ((1ULL << lane) - 1ULL));
        if (set && off < CCAP) ws[WS_CSC + v * CCAP + off] = ((rptr_s[c] + l) << 8) | c;
        cnt += (int)__popcll(mask);
    }
    if (cnt > CCAP) cnt = CCAP;
    if (lane == 0) ws[WS_CCNT + v] = cnt;
    if (lane >= cnt && lane < CCAP) ws[WS_CSC + v * CCAP + lane] = -1;
}

// ---- decode: one block per batch item; no atomics, 2 barriers/iter ----
__global__ __launch_bounds__(256) void ldpc_decode(const float* __restrict__ r,
                                                   const float* __restrict__ alpha,
                                                   const int* __restrict__ ws,
                                                   float* __restrict__ out) {
    __shared__ float r_s[VN];
    __shared__ float M_s[ECAP];
    __shared__ int   rptr_s[CN + 1];
    __shared__ float p1_s[CN], p2_s[CN];   // a * rowsign * {min1,min2}
    __shared__ int   am_s[CN];             // first-argmin edge index
    __shared__ int   csc_s[VN * CCAP];
    __shared__ int   ccnt_s[VN];

    const int b = blockIdx.x;
    const int t = threadIdx.x;

    for (int i = t; i < CN + 1; i += 256) rptr_s[i] = ws[WS_RPTR + i];
    for (int i = t; i < VN; i += 256) {
        r_s[i] = r[b * VN + i];
        ccnt_s[i] = ws[WS_CCNT + i];
    }
    for (int i = t; i < VN * CCAP; i += 256) csc_s[i] = ws[WS_CSC + i];
    __syncthreads();

    // M init = r on edges (via CSC)
    for (int i = t; i < VN * CCAP; i += 256) {
        const int entry = csc_s[i];
        if (entry >= 0) M_s[entry >> 8] = r_s[i >> 3];   // CCAP == 8
    }
    __syncthreads();

    for (int it = 0; it < NITER; ++it) {
        const float a = alpha[it];

        // Pass A: per-check {min1, min2, first-argmin, sign-product}
        for (int c = t; c < CN; c += 256) {
            const int s = rptr_s[c], epst = rptr_s[c + 1];
            float m1 = INFINITY, m2 = INFINITY, sg = 1.0f;
            int am = s;
            for (int e = s; e < epst; ++e) {
                const float m  = M_s[e];
                const float ab = fabsf(m);
                sg *= (m > 0.0f) ? 1.0f : ((m < 0.0f) ? -1.0f : 0.0f);
                if (ab < m1)      { m2 = m1; m1 = ab; am = e; }  // strict <: first occurrence
                else if (ab < m2) { m2 = ab; }
            }
            const float base = a * sg;
            p1_s[c] = base * m1;
            p2_s[c] = base * m2;
            am_s[c] = am;
        }
        __syncthreads();

        // Pass B: per-variable gather of its <=8 edges; fused col-sum + M update
        for (int v = t; v < VN; v += 256) {
            const int cnt = ccnt_s[v];
            float col = 0.0f;
            float Ej[CCAP];
            int   ej[CCAP];
            #pragma unroll
            for (int j = 0; j < CCAP; ++j) {
                float E = 0.0f; int e = -1;
                if (j < cnt) {
                    const int entry = csc_s[v * CCAP + j];
                    e = entry >> 8;
                    const int c = entry & 255;
                    const float m  = M_s[e];
                    const float sg = (m > 0.0f) ? 1.0f : ((m < 0.0f) ? -1.0f : 0.0f);
                    E = sg * ((e == am_s[c]) ? p2_s[c] : p1_s[c]);
                }
                Ej[j] = E; ej[j] = e;
                col += E;
            }
            if (it == NITER - 1) {
                out[b * VN + v] = r_s[v] + col;
            } else {
                const float mbase = col + r_s[v];
                #pragma unroll
                for (int j = 0; j < CCAP; ++j)
                    if (j < cnt) M_s[ej[j]] = mbase - Ej[j];
            }
        }
        __syncthreads();
    }
}

extern "C" void kernel_launch(void* const* d_in, const int* in_sizes, int n_in,
                              void* d_out, int out_size, void* d_ws, size_t ws_size,
                              hipStream_t stream) {
    const float* r     = (const float*)d_in[0];
    const float* alpha = (const float*)d_in[1];
    const float* H     = (const float*)d_in[2];
    float* out = (float*)d_out;
    int* ws    = (int*)d_ws;

    build_stage<<<CN, 64, 0, stream>>>(H, ws);
    build_csc<<<VN, 64, 0, stream>>>(ws);
    ldpc_decode<<<BN, 256, 0, stream>>>(r, alpha, ws, out);
}

// Round 4
// 29.784 us; speedup vs baseline: 5.3540x; 1.2199x over previous
//
#include <hip/hip_runtime.h>

#define CN 144
#define VN 576
#define BN 1024
#define NITER 3
#define RCAP 40      // row-weight capacity (avg 16, ~29 at +3 sigma); rmax clamped to this
#define CCAP 8       // column weight 4 (+ rare row-fix additions)
#define TPB 192      // 3 waves; 576/192 = exactly 3 columns per thread

// ws layout (ints):
#define WS_RLEN 0                    // [0,144)
#define WS_RMAX 160                  // [160]
#define WS_LOC  192                  // [192, +VN*CN) TRANSPOSED: loc[v*CN+c], -1 if no edge
#define WS_CSC  (192 + VN*CN)        // [+CCAP*VN] slot-major [j][v]: ((k*CN+c)<<8)|c, -1 sentinel
#define WS_CCNT (WS_CSC + CCAP*VN)   // [+VN]

// ---- build 1: per-row ballot compaction -> transposed loc table + row lengths ----
__global__ __launch_bounds__(64) void build_stage(const float* __restrict__ H,
                                                  int* __restrict__ ws) {
    const int c = blockIdx.x;          // 144 blocks
    const int lane = threadIdx.x;      // 64
    int base = 0;
    const float* row = H + c * VN;
    for (int ch = 0; ch < VN / 64; ++ch) {
        const int v = ch * 64 + lane;
        const bool set = row[v] > 0.5f;
        const unsigned long long mask = __ballot(set);
        const int off = base + (int)__popcll(mask & ((1ULL << lane) - 1ULL));
        ws[WS_LOC + v * CN + c] = set ? off : -1;   // slot index within row (ascending v)
        base += (int)__popcll(mask);
    }
    if (lane == 0) ws[WS_RLEN + c] = base;
}

// ---- build 2: one wave per column; ballot compaction into slot-major CSC ----
__global__ __launch_bounds__(64) void build_csc(int* __restrict__ ws) {
    const int v = blockIdx.x;          // 576 blocks
    const int lane = threadIdx.x;      // 64
    if (v == 0) {                      // publish rmax = max row length (clamped)
        int m = 0;
        for (int ch = 0; ch < 3; ++ch) {
            const int c = ch * 64 + lane;
            const int x = (c < CN) ? ws[WS_RLEN + c] : 0;
            m = max(m, x);
        }
        for (int d = 32; d; d >>= 1) m = max(m, __shfl_xor(m, d));
        if (lane == 0) ws[WS_RMAX] = min(m, RCAP);
    }
    int cnt = 0;
    for (int ch = 0; ch < 3; ++ch) {
        const int c = ch * 64 + lane;
        const int l = (c < CN) ? ws[WS_LOC + v * CN + c] : -1;   // coalesced
        const bool set = (l >= 0);
        const unsigned long long mask = __ballot(set);
        const int off = cnt + (int)__popcll(mask & ((1ULL << lane) - 1ULL));
        if (set && off < CCAP) ws[WS_CSC + off * VN + v] = ((l * CN + c) << 8) | c;
        cnt += (int)__popcll(mask);
    }
    if (cnt > CCAP) cnt = CCAP;
    if (lane == 0) ws[WS_CCNT + v] = cnt;
    if (lane >= cnt && lane < CCAP) ws[WS_CSC + lane * VN + v] = -1;
}

// ---- decode: one block per batch item; slot-major M (conflict-free pass A),
//      register CSC, float4-packed per-check results ----
__global__ __launch_bounds__(TPB) void ldpc_decode(const float* __restrict__ r,
                                                   const float* __restrict__ alpha,
                                                   const int* __restrict__ ws,
                                                   float* __restrict__ out) {
    __shared__ float  M_s[RCAP * CN];     // edge e = k*CN + c
    __shared__ float4 chk_s[CN];          // {p1, p2, am(bits), pad}

    const int b = blockIdx.x;
    const int t = threadIdx.x;
    const int rmax = ws[WS_RMAX];
    const float a_[NITER] = { alpha[0], alpha[1], alpha[2] };

    // per-thread columns v = t + q*TPB: load r and CSC into registers (coalesced)
    int   ent[3][CCAP];
    int   cnt[3];
    float rv[3];
    #pragma unroll
    for (int q = 0; q < 3; ++q) {
        const int v = t + q * TPB;
        rv[q]  = r[b * VN + v];
        cnt[q] = ws[WS_CCNT + v];
        #pragma unroll
        for (int j = 0; j < CCAP; ++j) ent[q][j] = ws[WS_CSC + j * VN + v];
    }
    // pad slots [rlen[c], rmax) = +INF  (sign +1, never a min: exact semantics)
    if (t < CN) {
        const int rl = ws[WS_RLEN + t];
        for (int k = rl; k < rmax; ++k) M_s[k * CN + t] = INFINITY;
    }
    // M init = r on real edges (disjoint from pad slots -> no barrier needed between)
    #pragma unroll
    for (int q = 0; q < 3; ++q) {
        #pragma unroll
        for (int j = 0; j < CCAP; ++j)
            if (j < cnt[q]) M_s[ent[q][j] >> 8] = rv[q];
    }
    __syncthreads();

    #pragma unroll
    for (int it = 0; it < NITER; ++it) {
        const float a = a_[it];

        // Pass A: per-check {min1, min2, first-argmin, sign-product}; lane=c consecutive
        if (t < CN) {
            float m1 = INFINITY, m2 = INFINITY, sg = 1.0f;
            int am = t;   // k=0 edge id (row weight >= 2, slot 0 always real)
            for (int k = 0; k < rmax; ++k) {
                const float m  = M_s[k * CN + t];
                const float ab = fabsf(m);
                sg *= (m > 0.0f) ? 1.0f : ((m < 0.0f) ? -1.0f : 0.0f);
                if (ab < m1)      { m2 = m1; m1 = ab; am = k * CN + t; } // strict <: first occurrence
                else if (ab < m2) { m2 = ab; }
            }
            const float base = a * sg;
            chk_s[t] = make_float4(base * m1, base * m2, __int_as_float(am), 0.0f);
        }
        __syncthreads();

        // Pass B: per-column gather (<=8 edges, register CSC); fused col-sum + M update
        #pragma unroll
        for (int q = 0; q < 3; ++q) {
            float col = 0.0f;
            float Ej[CCAP];
            #pragma unroll
            for (int j = 0; j < CCAP; ++j) {
                float E = 0.0f;
                if (j < cnt[q]) {
                    const int entry = ent[q][j];
                    const int e = entry >> 8, c = entry & 255;
                    const float  m  = M_s[e];
                    const float  sg = (m > 0.0f) ? 1.0f : ((m < 0.0f) ? -1.0f : 0.0f);
                    const float4 ck = chk_s[c];
                    E = sg * ((e == __float_as_int(ck.z)) ? ck.y : ck.x);
                }
                Ej[j] = E;
                col += E;
            }
            if (it == NITER - 1) {
                out[b * VN + t + q * TPB] = rv[q] + col;
            } else {
                const float mb = col + rv[q];
                #pragma unroll
                for (int j = 0; j < CCAP; ++j)
                    if (j < cnt[q]) M_s[ent[q][j] >> 8] = mb - Ej[j];
            }
        }
        if (it < NITER - 1) __syncthreads();
    }
}

extern "C" void kernel_launch(void* const* d_in, const int* in_sizes, int n_in,
                              void* d_out, int out_size, void* d_ws, size_t ws_size,
                              hipStream_t stream) {
    const float* r     = (const float*)d_in[0];
    const float* alpha = (const float*)d_in[1];
    const float* H     = (const float*)d_in[2];
    float* out = (float*)d_out;
    int* ws    = (int*)d_ws;

    build_stage<<<CN, 64, 0, stream>>>(H, ws);
    build_csc<<<VN, 64, 0, stream>>>(ws);
    ldpc_decode<<<BN, TPB, 0, stream>>>(r, alpha, ws, out);
}

// Round 5
// 24.858 us; speedup vs baseline: 6.4150x; 1.1982x over previous
//
#include <hip/hip_runtime.h>
#include <stdint.h>

#define CN 144
#define VN 576
#define BN 1024
#define NITER 3
#define RCAP 40      // row-weight capacity, multiple of 4 (actual max ~28)
#define CCAP 8       // column-weight capacity (actual 4, + rare row-fix adds)
#define TPB 192      // 3 waves; 576/192 = exactly 3 columns per thread

// ws layout (ints):
#define WS_RLEN 0                    // [0,144)
#define WS_LOC  192                  // [+VN*CN) transposed: loc[v*CN+c] = slot in row, -1 if none
#define WS_CSC  (192 + VN*CN)        // [+CCAP*VN) slot-major [j][v] = edge index e (quad formula)
#define WS_CCNT (WS_CSC + CCAP*VN)   // [+VN)

// edge id for (row-slot l, check c), quad layout: M element (l,c) lives at
// float index ((l>>2)*CN + c)*4 + (l&3)  -> lane-consecutive float4 per (l>>2, c)
__device__ __forceinline__ int edge_id(int l, int c) {
    return (((l >> 2) * CN + c) << 2) | (l & 3);
}

// ---- build 1: per-row ballot compaction -> transposed loc table + row lengths ----
__global__ __launch_bounds__(64) void build_stage(const float* __restrict__ H,
                                                  int* __restrict__ ws) {
    const int c = blockIdx.x;          // 144 blocks
    const int lane = threadIdx.x;      // 64
    int base = 0;
    const float* row = H + c * VN;
    for (int ch = 0; ch < VN / 64; ++ch) {
        const int v = ch * 64 + lane;
        const bool set = row[v] > 0.5f;
        const unsigned long long mask = __ballot(set);
        const int off = base + (int)__popcll(mask & ((1ULL << lane) - 1ULL));
        ws[WS_LOC + v * CN + c] = set ? off : -1;   // ascending-v slot order
        base += (int)__popcll(mask);
    }
    if (lane == 0) ws[WS_RLEN + c] = base;
}

// ---- build 2: one wave per column; ballot compaction into slot-major CSC ----
__global__ __launch_bounds__(64) void build_csc(int* __restrict__ ws) {
    const int v = blockIdx.x;          // 576 blocks
    const int lane = threadIdx.x;      // 64
    int cnt = 0;
    for (int ch = 0; ch < 3; ++ch) {
        const int c = ch * 64 + lane;
        const int l = (c < CN) ? ws[WS_LOC + v * CN + c] : -1;   // coalesced
        const bool set = (l >= 0) && (l < RCAP);
        const unsigned long long mask = __ballot(set);
        const int off = cnt + (int)__popcll(mask & ((1ULL << lane) - 1ULL));
        if (set && off < CCAP) ws[WS_CSC + off * VN + v] = edge_id(l, c);
        cnt += (int)__popcll(mask);
    }
    if (cnt > CCAP) cnt = CCAP;
    if (lane == 0) ws[WS_CCNT + v] = cnt;
    if (lane >= cnt && lane < CCAP) ws[WS_CSC + lane * VN + v] = 0;  // defined, unused
}

// ---- decode: one block per batch item ----
__global__ __launch_bounds__(TPB) void ldpc_decode(const float* __restrict__ r,
                                                   const float* __restrict__ alpha,
                                                   const int* __restrict__ ws,
                                                   float* __restrict__ out) {
    __shared__ float4 M4[(RCAP / 4) * CN];
    float* const Mf = reinterpret_cast<float*>(M4);

    const int b = blockIdx.x;
    const int t = threadIdx.x;
    const float a_[NITER] = { alpha[0], alpha[1], alpha[2] };

    // per-thread columns v = t + q*TPB
    int   ent4[3][4], entX[3][4];
    int   cnt[3];
    float rv[3];
    #pragma unroll
    for (int q = 0; q < 3; ++q) {
        const int v = t + q * TPB;
        rv[q]  = r[b * VN + v];
        cnt[q] = ws[WS_CCNT + v];
        #pragma unroll
        for (int j = 0; j < 4; ++j) ent4[q][j] = ws[WS_CSC + j * VN + v];
    }
    const int rl = (t < CN) ? ws[WS_RLEN + t] : 0;
    const int any_hi = __syncthreads_or((cnt[0] > 4) | (cnt[1] > 4) | (cnt[2] > 4));
    if (any_hi) {
        #pragma unroll
        for (int q = 0; q < 3; ++q)
            #pragma unroll
            for (int j = 0; j < 4; ++j) entX[q][j] = ws[WS_CSC + (4 + j) * VN + t + q * TPB];
    }

    // INF pads up to quad boundary (preserved across iterations)
    if (t < CN) {
        const int rpad = (rl + 3) & ~3;
        for (int k = rl; k < rpad; ++k) Mf[edge_id(k, t)] = INFINITY;
    }
    // M init = r on real edges (disjoint from pads)
    #pragma unroll
    for (int q = 0; q < 3; ++q) {
        #pragma unroll
        for (int j = 0; j < 4; ++j) if (j < cnt[q]) Mf[ent4[q][j]] = rv[q];
    }
    if (any_hi) {
        #pragma unroll
        for (int q = 0; q < 3; ++q) {
            #pragma unroll
            for (int j = 0; j < 4; ++j) if (4 + j < cnt[q]) Mf[entX[q][j]] = rv[q];
        }
    }
    __syncthreads();

    #pragma unroll
    for (int it = 0; it < NITER; ++it) {
        const float a = a_[it];

        // Pass A: per-check min1/min2/first-argmin/sign-product (abs as uint cmp,
        // sign as xor), then rewrite own slots with E in place.
        if (t < CN) {
            uint32_t m1 = 0x7fffffffu, m2 = 0x7fffffffu, sg = 0u;
            int am = -1;
            const int nq = (rl + 3) >> 2;
            for (int q4 = 0; q4 < nq; ++q4) {
                const float4 mv = M4[q4 * CN + t];
                const float* mvp = reinterpret_cast<const float*>(&mv);
                #pragma unroll
                for (int j = 0; j < 4; ++j) {
                    const uint32_t mb = __float_as_uint(mvp[j]);
                    const uint32_t ab = mb & 0x7fffffffu;   // INF pads: 0x7f800000, never win
                    sg ^= mb;
                    const bool lt = ab < m1;                // strict: first-occurrence argmin
                    const uint32_t mn2 = (m2 < ab) ? m2 : ab;
                    m2 = lt ? m1 : mn2;
                    m1 = lt ? ab : m1;
                    am = lt ? (q4 * 4 + j) : am;
                }
            }
            sg &= 0x80000000u;                              // pads contribute sign +1: exact
            const uint32_t p1b = __float_as_uint(a * __uint_as_float(m1)) ^ sg;
            const uint32_t p2b = __float_as_uint(a * __uint_as_float(m2)) ^ sg;

            const int nqf = rl >> 2;                        // full quads: unpredicated
            for (int q4 = 0; q4 < nqf; ++q4) {
                const float4 mv = M4[q4 * CN + t];
                const float* mvp = reinterpret_cast<const float*>(&mv);
                float ev[4];
                #pragma unroll
                for (int j = 0; j < 4; ++j) {
                    const uint32_t mb = __float_as_uint(mvp[j]);
                    const uint32_t ps = ((q4 * 4 + j) == am) ? p2b : p1b;
                    ev[j] = __uint_as_float(ps ^ (mb & 0x80000000u));
                }
                M4[q4 * CN + t] = make_float4(ev[0], ev[1], ev[2], ev[3]);
            }
            if (rl & 3) {                                   // tail quad: preserve INF pads
                const int q4 = nqf;
                const float4 mv = M4[q4 * CN + t];
                const float* mvp = reinterpret_cast<const float*>(&mv);
                float ev[4];
                #pragma unroll
                for (int j = 0; j < 4; ++j) {
                    const int k = q4 * 4 + j;
                    const uint32_t mb = __float_as_uint(mvp[j]);
                    const uint32_t ps = (k == am) ? p2b : p1b;
                    ev[j] = (k < rl) ? __uint_as_float(ps ^ (mb & 0x80000000u)) : mvp[j];
                }
                M4[q4 * CN + t] = make_float4(ev[0], ev[1], ev[2], ev[3]);
            }
        }
        __syncthreads();

        // Pass B: per-column gather of E, col-sum (ascending c), fused M update
        #pragma unroll
        for (int q = 0; q < 3; ++q) {
            float E4[4], EX[4];
            float col = 0.0f;
            #pragma unroll
            for (int j = 0; j < 4; ++j) {
                E4[j] = (j < cnt[q]) ? Mf[ent4[q][j]] : 0.0f;
                col += E4[j];
            }
            if (any_hi) {
                #pragma unroll
                for (int j = 0; j < 4; ++j) {
                    EX[j] = (4 + j < cnt[q]) ? Mf[entX[q][j]] : 0.0f;
                    col += EX[j];
                }
            }
            if (it == NITER - 1) {
                out[b * VN + t + q * TPB] = rv[q] + col;
            } else {
                const float mb = col + rv[q];
                #pragma unroll
                for (int j = 0; j < 4; ++j) if (j < cnt[q]) Mf[ent4[q][j]] = mb - E4[j];
                if (any_hi) {
                    #pragma unroll
                    for (int j = 0; j < 4; ++j) if (4 + j < cnt[q]) Mf[entX[q][j]] = mb - EX[j];
                }
            }
        }
        if (it < NITER - 1) __syncthreads();
    }
}

extern "C" void kernel_launch(void* const* d_in, const int* in_sizes, int n_in,
                              void* d_out, int out_size, void* d_ws, size_t ws_size,
                              hipStream_t stream) {
    const float* r     = (const float*)d_in[0];
    const float* alpha = (const float*)d_in[1];
    const float* H     = (const float*)d_in[2];
    float* out = (float*)d_out;
    int* ws    = (int*)d_ws;

    build_stage<<<CN, 64, 0, stream>>>(H, ws);
    build_csc<<<VN, 64, 0, stream>>>(ws);
    ldpc_decode<<<BN, TPB, 0, stream>>>(r, alpha, ws, out);
}